// Round 3
// baseline (251.562 us; speedup 1.0000x reference)
//
#include <hip/hip_runtime.h>

// IRFDeconv3D: out[b,p,t] = sum_{tau<=t} data[b,p,tau] * knorm[b,t-tau]
// == per-batch GEMM A[16384x256] @ Toeplitz(knorm)[256x256], keep n<256.
//
// v3: fight latency with explicit in-register MLP (v2 post-mortem: VGPR=68,
// allocator serialized every load; all pipes <4% busy).
//  - Whole A quarter-row preloaded via 16 back-to-back dwordx4, converted
//    once to 32 bf16 VGPRs (zero A traffic inside the K-loop).
//  - B fragments double-buffered in registers: slab kk+1's loads issue
//    before slab kk's MFMAs; ordered vmcnt keeps them in flight across the
//    consume (no barriers anywhere, so the compiler can do fine-grained
//    waits). Triangular skip (tile j < 2*kk is all-zero) at compile time.

typedef __attribute__((ext_vector_type(8))) short short8;
typedef __attribute__((ext_vector_type(4))) float floatx4;

#define T_BINS 256
#define PIX_PER_B (128 * 128)

__device__ inline unsigned short f2bf(float f) {
    unsigned int u = __float_as_uint(f);
    u += 0x7fffu + ((u >> 16) & 1u);   // round-to-nearest-even
    return (unsigned short)(u >> 16);
}

// W[b][kk][n][kl] (bf16) = knorm[n - (32*kk+kl)] if n >= k else 0
__global__ __launch_bounds__(256) void build_W(const float* __restrict__ irf,
                                               unsigned short* __restrict__ W) {
    __shared__ float red[256];
    __shared__ float knorm[256];
    const int b = blockIdx.x >> 5;
    const int z = blockIdx.x & 31;
    const int t = threadIdx.x;
    float v = irf[b * T_BINS + t];
    red[t] = v;
    __syncthreads();
    for (int s = 128; s > 0; s >>= 1) {
        if (t < s) red[t] = fmaxf(red[t], red[t + s]);
        __syncthreads();
    }
    knorm[t] = v / red[0];
    __syncthreads();
    unsigned short* Wb = W + b * 65536;
#pragma unroll
    for (int i = 0; i < 8; i++) {
        int e = z * 2048 + i * 256 + t;   // coalesced
        int kk = e >> 13;
        int n = (e >> 5) & 255;
        int kl = e & 31;
        int k = kk * 32 + kl;
        Wb[e] = (n >= k) ? f2bf(knorm[n - k]) : (unsigned short)0;
    }
}

__global__ __launch_bounds__(256) void conv_gemm(const float* __restrict__ data,
                                                 const unsigned short* __restrict__ W,
                                                 float* __restrict__ out) {
    const int b = blockIdx.x >> 8;        // 256 m-tiles per batch
    const int mt = blockIdx.x & 255;
    const int t = threadIdx.x;
    const int w = t >> 6;                 // wave id (0..3); waves independent
    const int l = t & 63;
    const int lq = l >> 4;                // quad (0..3)
    const int lm = l & 15;

    const int row = mt * 64 + w * 16 + lm;            // this lane's A row
    const float* Arow = data + ((size_t)b * PIX_PER_B + row) * T_BINS;
    const unsigned short* Wb = W + b * 65536;

    // ---- Phase 1: issue all 16 A loads (independent, stay in flight) ----
    float4 av[16];
#pragma unroll
    for (int kk = 0; kk < 8; kk++) {
        av[2 * kk]     = *(const float4*)(Arow + kk * 32 + lq * 8);
        av[2 * kk + 1] = *(const float4*)(Arow + kk * 32 + lq * 8 + 4);
    }

    // ---- Phase 2: issue B group for kk=0 (16 frags, independent) ----
    short8 bbuf[2][16];
#pragma unroll
    for (int j = 0; j < 16; j++)
        bbuf[0][j] = *(const short8*)(Wb + (16 * j + lm) * 32 + lq * 8);

    // ---- Phase 3: convert A (waits only on A loads; B stays in flight) ----
    short8 a[8];
#pragma unroll
    for (int kk = 0; kk < 8; kk++) {
        const float4 va = av[2 * kk];
        const float4 vb = av[2 * kk + 1];
        a[kk][0] = (short)f2bf(va.x); a[kk][1] = (short)f2bf(va.y);
        a[kk][2] = (short)f2bf(va.z); a[kk][3] = (short)f2bf(va.w);
        a[kk][4] = (short)f2bf(vb.x); a[kk][5] = (short)f2bf(vb.y);
        a[kk][6] = (short)f2bf(vb.z); a[kk][7] = (short)f2bf(vb.w);
    }

    floatx4 acc[16];
#pragma unroll
    for (int j = 0; j < 16; j++) acc[j] = (floatx4){0.f, 0.f, 0.f, 0.f};

    // ---- Main loop: prefetch slab kk+1's frags, then MFMA slab kk ----
#pragma unroll
    for (int kk = 0; kk < 8; kk++) {
        const int cur = kk & 1;
        const int nxt = cur ^ 1;
        if (kk < 7) {
#pragma unroll
            for (int j = 0; j < 16; j++) {
                if (j >= 2 * (kk + 1)) {
                    bbuf[nxt][j] = *(const short8*)(Wb + (kk + 1) * 8192 +
                                                    (16 * j + lm) * 32 + lq * 8);
                }
            }
        }
#pragma unroll
        for (int j = 0; j < 16; j++) {
            if (j >= 2 * kk) {
                acc[j] = __builtin_amdgcn_mfma_f32_16x16x32_bf16(a[kk], bbuf[cur][j],
                                                                 acc[j], 0, 0, 0);
            }
        }
    }

    // ---- Epilogue: C/D layout col = lm, row = lq*4 + r ----
    float* Ob = out + ((size_t)b * PIX_PER_B + mt * 64 + w * 16) * T_BINS;
#pragma unroll
    for (int j = 0; j < 16; j++) {
#pragma unroll
        for (int r = 0; r < 4; r++) {
            Ob[(size_t)(lq * 4 + r) * T_BINS + 16 * j + lm] = acc[j][r];
        }
    }
}

extern "C" void kernel_launch(void* const* d_in, const int* in_sizes, int n_in,
                              void* d_out, int out_size, void* d_ws, size_t ws_size,
                              hipStream_t stream) {
    const float* data = (const float*)d_in[0];   // [8,128,128,256,1] fp32
    const float* irf  = (const float*)d_in[1];   // [8,1,1,256,1] fp32
    float* outp = (float*)d_out;                 // [8,128,128,256,1] fp32
    unsigned short* W = (unsigned short*)d_ws;   // 8*8*256*32 bf16 = 1 MiB

    build_W<<<256, 256, 0, stream>>>(irf, W);
    conv_gemm<<<2048, 256, 0, stream>>>(data, W, outp);
}

// Round 4
// 249.479 us; speedup vs baseline: 1.0084x; 1.0084x over previous
//
#include <hip/hip_runtime.h>

// IRFDeconv3D: out[b,p,t] = sum_{tau<=t} data[b,p,tau] * knorm[b,t-tau]
// == per-batch GEMM A[16384x256] @ Toeplitz(knorm)[256x256], keep n<256.
//
// v4: v3's register pipeline never materialized (VGPR_Count=68: the
// scheduler sank all loads to their uses and serialized ~88 L2 latencies
// per wave). This version FORCES the pipeline:
//  - __launch_bounds__(256,1): allow up to 512 VGPRs, don't schedule for
//    occupancy.
//  - __builtin_amdgcn_sched_barrier(0) at stage boundaries: prefetch for
//    slab kk+2 (A and B, ~16 independent VMEM ops) must issue before slab
//    kk+1 is consumed -> fine-grained vmcnt waits, loads in flight across
//    consumption. No LDS, no s_barrier anywhere.
//  - A double-buffered per-slab (not whole-row) to keep peak liveness
//    ~220 VGPR -> 2 waves/SIMD.
// Triangular skip (n-tile j < 2*kk is all-zero) resolved at compile time.

typedef __attribute__((ext_vector_type(8))) short short8;
typedef __attribute__((ext_vector_type(4))) float floatx4;

#define T_BINS 256
#define PIX_PER_B (128 * 128)

__device__ inline unsigned short f2bf(float f) {
    unsigned int u = __float_as_uint(f);
    u += 0x7fffu + ((u >> 16) & 1u);   // round-to-nearest-even
    return (unsigned short)(u >> 16);
}

// W[b][kk][n][kl] (bf16) = knorm[n - (32*kk+kl)] if n >= k else 0
__global__ __launch_bounds__(256) void build_W(const float* __restrict__ irf,
                                               unsigned short* __restrict__ W) {
    __shared__ float red[256];
    __shared__ float knorm[256];
    const int b = blockIdx.x >> 5;
    const int z = blockIdx.x & 31;
    const int t = threadIdx.x;
    float v = irf[b * T_BINS + t];
    red[t] = v;
    __syncthreads();
    for (int s = 128; s > 0; s >>= 1) {
        if (t < s) red[t] = fmaxf(red[t], red[t + s]);
        __syncthreads();
    }
    knorm[t] = v / red[0];
    __syncthreads();
    unsigned short* Wb = W + b * 65536;
#pragma unroll
    for (int i = 0; i < 8; i++) {
        int e = z * 2048 + i * 256 + t;   // coalesced
        int kk = e >> 13;
        int n = (e >> 5) & 255;
        int kl = e & 31;
        int k = kk * 32 + kl;
        Wb[e] = (n >= k) ? f2bf(knorm[n - k]) : (unsigned short)0;
    }
}

__device__ inline short8 cvt_a(float4 lo, float4 hi) {
    short8 a;
    a[0] = (short)f2bf(lo.x); a[1] = (short)f2bf(lo.y);
    a[2] = (short)f2bf(lo.z); a[3] = (short)f2bf(lo.w);
    a[4] = (short)f2bf(hi.x); a[5] = (short)f2bf(hi.y);
    a[6] = (short)f2bf(hi.z); a[7] = (short)f2bf(hi.w);
    return a;
}

__global__ __launch_bounds__(256, 1) void conv_gemm(const float* __restrict__ data,
                                                    const unsigned short* __restrict__ W,
                                                    float* __restrict__ out) {
    const int b = blockIdx.x >> 8;        // 256 m-tiles per batch
    const int mt = blockIdx.x & 255;
    const int t = threadIdx.x;
    const int w = t >> 6;                 // wave id (0..3); waves independent
    const int l = t & 63;
    const int lq = l >> 4;                // quad (0..3)
    const int lm = l & 15;

    const int row = mt * 64 + w * 16 + lm;            // this lane's A row
    const float* Arow = data + ((size_t)b * PIX_PER_B + row) * T_BINS;
    const unsigned short* Wb = W + b * 65536;

    float4 av[2][2];       // A raw, double-buffered per slab
    short8 bbuf[2][16];    // B frags, double-buffered per slab

    // ---- prologue: issue slabs 0 and 1 ----
    av[0][0] = *(const float4*)(Arow + 0 * 32 + lq * 8);
    av[0][1] = *(const float4*)(Arow + 0 * 32 + lq * 8 + 4);
    av[1][0] = *(const float4*)(Arow + 1 * 32 + lq * 8);
    av[1][1] = *(const float4*)(Arow + 1 * 32 + lq * 8 + 4);
#pragma unroll
    for (int j = 0; j < 16; j++)
        bbuf[0][j] = *(const short8*)(Wb + (16 * j + lm) * 32 + lq * 8);
#pragma unroll
    for (int j = 2; j < 16; j++)
        bbuf[1][j] = *(const short8*)(Wb + 8192 + (16 * j + lm) * 32 + lq * 8);
    __builtin_amdgcn_sched_barrier(0);

    floatx4 acc[16];
#pragma unroll
    for (int j = 0; j < 16; j++) acc[j] = (floatx4){0.f, 0.f, 0.f, 0.f};

#pragma unroll
    for (int kk = 0; kk < 8; kk++) {
        const int cur = kk & 1;
        // consume slab kk
        short8 a = cvt_a(av[cur][0], av[cur][1]);
#pragma unroll
        for (int j = 0; j < 16; j++) {
            if (j >= 2 * kk) {
                acc[j] = __builtin_amdgcn_mfma_f32_16x16x32_bf16(a, bbuf[cur][j],
                                                                 acc[j], 0, 0, 0);
            }
        }
        __builtin_amdgcn_sched_barrier(0);
        // prefetch slab kk+2 into the buffer just freed
        if (kk + 2 <= 7) {
            av[cur][0] = *(const float4*)(Arow + (kk + 2) * 32 + lq * 8);
            av[cur][1] = *(const float4*)(Arow + (kk + 2) * 32 + lq * 8 + 4);
#pragma unroll
            for (int j = 0; j < 16; j++) {
                if (j >= 2 * (kk + 2)) {
                    bbuf[cur][j] = *(const short8*)(Wb + (kk + 2) * 8192 +
                                                    (16 * j + lm) * 32 + lq * 8);
                }
            }
        }
        __builtin_amdgcn_sched_barrier(0);
    }

    // ---- epilogue: C/D layout col = lm, row = lq*4 + r ----
    float* Ob = out + ((size_t)b * PIX_PER_B + mt * 64 + w * 16) * T_BINS;
#pragma unroll
    for (int j = 0; j < 16; j++) {
#pragma unroll
        for (int r = 0; r < 4; r++) {
            Ob[(size_t)(lq * 4 + r) * T_BINS + 16 * j + lm] = acc[j][r];
        }
    }
}

extern "C" void kernel_launch(void* const* d_in, const int* in_sizes, int n_in,
                              void* d_out, int out_size, void* d_ws, size_t ws_size,
                              hipStream_t stream) {
    const float* data = (const float*)d_in[0];   // [8,128,128,256,1] fp32
    const float* irf  = (const float*)d_in[1];   // [8,1,1,256,1] fp32
    float* outp = (float*)d_out;                 // [8,128,128,256,1] fp32
    unsigned short* W = (unsigned short*)d_ws;   // 8*8*256*32 bf16 = 1 MiB

    build_W<<<256, 256, 0, stream>>>(irf, W);
    conv_gemm<<<2048, 256, 0, stream>>>(data, W, outp);
}